// Round 1
// 1936.178 us; speedup vs baseline: 1.1186x; 1.1186x over previous
//
#include <hip/hip_runtime.h>
#include <hip/hip_bf16.h>
#include <math.h>

// ---------------------------------------------------------------------------
// VisionExpertAttention on MI355X (gfx950) — round 3
//   * expert ROUTING via device-side scan + gathered rows (halves GEMM FLOPs)
//   * GEMM round 3 changes:
//       - 1-D grid + bijective XCD swizzle (T1), bm-inner ordering: each XCD
//         owns a contiguous chunk of bn-panels -> B-panel L2-resident for 33
//         consecutive blocks, A L3-resident. Target: FETCH 2.9GB -> <1GB.
//       - 2-phase double-buffered K-loop (T3 minimum recipe): stage tile t+1
//         BEFORE computing tile t, single vmcnt(0)+s_barrier per K-step
//         (no compiler-inserted drain between stage and compute). Static
//         even/odd buffers so alias analysis can't force an early vmcnt.
//       - setprio(1) around the MFMA cluster (template default).
//   * XOR-swizzled LDS layouts kept from round 2 (2-way conflicts = free)
// ---------------------------------------------------------------------------

typedef __bf16 bf16_t;
typedef __bf16 bf16x8 __attribute__((ext_vector_type(8)));
typedef __bf16 bf16x4 __attribute__((ext_vector_type(4)));
typedef float  f32x4  __attribute__((ext_vector_type(4)));

#define BSZ   2
#define SEQ   2048
#define NTOK  (BSZ * SEQ)     // 4096
#define MPAD  (NTOK + 128)    // 4224 gathered rows (vision padded to 128)
#define HID   4096
#define NH    32
#define HD    128
#define QKV3  (3 * HID)       // 12288
#define GM    (MPAD / 128)    // 33 M-tiles

__device__ __forceinline__ void gld_lds16(const bf16_t* g, bf16_t* l) {
  __builtin_amdgcn_global_load_lds(
      (const __attribute__((address_space(1))) unsigned int*)g,
      (__attribute__((address_space(3))) unsigned int*)l, 16, 0, 0);
}

// ---------------------------------------------------------------- cast f32->bf16
__global__ __launch_bounds__(256) void castk(const float* __restrict__ in,
                                             bf16_t* __restrict__ out,
                                             long long n) {
  long long i = ((long long)blockIdx.x * 256 + threadIdx.x) * 4;
  if (i >= n) return;
  float4 v = *(const float4*)(in + i);
  bf16x4 o;
  o[0] = (bf16_t)v.x; o[1] = (bf16_t)v.y; o[2] = (bf16_t)v.z; o[3] = (bf16_t)v.w;
  *(bf16x4*)(out + i) = o;
}

// ------------------------------------------------- cast + gather hidden rows
__global__ __launch_bounds__(256) void cast_gather(const float* __restrict__ in,
                                                   bf16_t* __restrict__ out,
                                                   const int* __restrict__ ginv) {
  long long i = ((long long)blockIdx.x * 256 + threadIdx.x) * 4;
  int token = (int)(i >> 12);        // HID = 4096
  int col = (int)(i & 4095);
  float4 v = *(const float4*)(in + i);
  bf16x4 o;
  o[0] = (bf16_t)v.x; o[1] = (bf16_t)v.y; o[2] = (bf16_t)v.z; o[3] = (bf16_t)v.w;
  *(bf16x4*)(out + (size_t)ginv[token] * HID + col) = o;
}

// ---------------------------------------------------------------- routing scan
// vision iff tt[l]==1 && tt[l+1]==1 (l < SEQ-1). vision tokens -> rows
// [0,nv), pad to 128; language -> [nvpad, nvpad+nl). perm_src[dst]=token or
// -1 (pad), ginv[token]=dst, meta[0]=nvpad/128 (# vision M-tiles).
__global__ __launch_bounds__(1024) void scan_kernel(const int* __restrict__ tt,
                                                    int* __restrict__ perm_src,
                                                    int* __restrict__ ginv,
                                                    int* __restrict__ meta) {
  __shared__ int sums[1024];
  const int t = threadIdx.x;
  for (int i = t; i < MPAD; i += 1024) perm_src[i] = -1;
  int v[4], s = 0;
#pragma unroll
  for (int j = 0; j < 4; j++) {
    int tok = t * 4 + j;
    int l = tok & (SEQ - 1);
    int vis = (l < SEQ - 1) && (tt[tok] == 1) && (tt[tok + 1] == 1);
    v[j] = vis; s += vis;
  }
  sums[t] = s;
  __syncthreads();
  for (int off = 1; off < 1024; off <<= 1) {
    int x = sums[t];
    int y = (t >= off) ? sums[t - off] : 0;
    __syncthreads();
    sums[t] = x + y;
    __syncthreads();
  }
  const int nv = sums[1023];
  const int nvpad = (nv + 127) & ~127;
  int pv = sums[t] - s;  // vision count strictly before this thread's tokens
#pragma unroll
  for (int j = 0; j < 4; j++) {
    int tok = t * 4 + j;
    int dst;
    if (v[j]) { dst = pv; pv++; }
    else      { dst = nvpad + (tok - pv); }
    perm_src[dst] = tok;
    ginv[tok] = dst;
  }
  if (t == 0) meta[0] = nvpad >> 7;
}

// ------------------------------------------- routed GEMM C = A_g @ B_e^T
// A [MPAD,K] gathered bf16; B chosen per M-tile (vision tiles first).
// Epilogue scatters row perm_src[row_g] (skip -1). Swizzled LDS: chunk of
// row r stored at chunkpos ^ ((r>>1)&3)  ->  2-way (free) frag reads.
// 1-D grid, XCD-chunked bn-panels, bm-inner. 2-phase pipelined K-loop.
#define GEMM_STAGE(AS, BS, kt)                              \
  do {                                                      \
    gld_lds16(a0 + (kt), &AS[(tid & ~63) * 8]);             \
    gld_lds16(a1 + (kt), &AS[(256 + (tid & ~63)) * 8]);     \
    gld_lds16(b0 + (kt), &BS[(tid & ~63) * 8]);             \
    gld_lds16(b1 + (kt), &BS[(256 + (tid & ~63)) * 8]);     \
  } while (0)

#define GEMM_COMPUTE(AS, BS)                                                 \
  do {                                                                       \
    bf16x8 af[4], bfr[4];                                                    \
    _Pragma("unroll") for (int i = 0; i < 4; i++)                            \
        af[i] = *(const bf16x8*)&AS[(wm + i * 16 + lr) * 32 + pp];           \
    _Pragma("unroll") for (int j = 0; j < 4; j++)                            \
        bfr[j] = *(const bf16x8*)&BS[(wn + j * 16 + lr) * 32 + pp];          \
    __builtin_amdgcn_s_setprio(1);                                          \
    _Pragma("unroll") for (int i = 0; i < 4; i++)                            \
        _Pragma("unroll") for (int j = 0; j < 4; j++)                        \
            acc[i][j] = __builtin_amdgcn_mfma_f32_16x16x32_bf16(             \
                af[i], bfr[j], acc[i][j], 0, 0, 0);                          \
    __builtin_amdgcn_s_setprio(0);                                          \
  } while (0)

#define GEMM_BOUNDARY                                       \
  do {                                                      \
    asm volatile("s_waitcnt vmcnt(0)" ::: "memory");        \
    __builtin_amdgcn_s_barrier();                           \
  } while (0)

template <int OUT_F32>
__global__ __launch_bounds__(256) void gemm_routed(
    const bf16_t* __restrict__ A, const bf16_t* __restrict__ Bv,
    const bf16_t* __restrict__ Bl, void* __restrict__ Cout, int N, int K,
    const int* __restrict__ perm_src, const int* __restrict__ meta) {
  __shared__ bf16_t As0[128 * 32];
  __shared__ bf16_t Bs0[128 * 32];
  __shared__ bf16_t As1[128 * 32];
  __shared__ bf16_t Bs1[128 * 32];
  const int tid = threadIdx.x;

  // T1: bijective XCD chunking. Consecutive wgid on one XCD walk bm fastest
  // within a bn-panel -> B-panel reused 33x from L2, A streamed from L3.
  const int nwg = gridDim.x;
  const int q = nwg >> 3, r = nwg & 7;
  const int xcd = blockIdx.x & 7, pos = blockIdx.x >> 3;
  const int wgid = (xcd < r ? xcd * (q + 1) : r * (q + 1) + (xcd - r) * q) + pos;
  const int bm = wgid % GM;
  const int bn = wgid / GM;

  const bf16_t* __restrict__ B = (bm < meta[0]) ? Bv : Bl;
  const int wv = tid >> 6, lane = tid & 63, lr = lane & 15, quad = lane >> 4;
  const int wm = (wv >> 1) * 64, wn = (wv & 1) * 64;

  // staging: LDS slot tid = row tid>>2, chunkpos tid&3; load the global
  // chunk that belongs there under the swizzle
  const int r0 = tid >> 2;
  const int c0 = ((tid & 3) ^ ((tid >> 3) & 3)) * 8;
  const bf16_t* a0 = A + (size_t)(bm * 128 + r0) * K + c0;
  const bf16_t* a1 = A + (size_t)(bm * 128 + r0 + 64) * K + c0;
  const bf16_t* b0 = B + (size_t)(bn * 128 + r0) * K + c0;
  const bf16_t* b1 = B + (size_t)(bn * 128 + r0 + 64) * K + c0;

  // fragment read chunkpos: quad ^ ((row>>1)&3); row = wm+i*16+lr with
  // wm+i*16 a multiple of 16 -> (row>>1)&3 == (lr>>1)&3, lane-constant.
  const int pp = (quad ^ ((lr >> 1) & 3)) * 8;

  f32x4 acc[4][4] = {};

  // 2-phase pipeline, K/32 steps (even, >= 2: K = 4096 -> 128 steps).
  GEMM_STAGE(As0, Bs0, 0);
  GEMM_BOUNDARY;
  int kt = 32;
  for (int s = 0; s < (K >> 5) - 2; s += 2) {
    GEMM_STAGE(As1, Bs1, kt);        // step s+1
    GEMM_COMPUTE(As0, Bs0);          // step s
    GEMM_BOUNDARY;
    GEMM_STAGE(As0, Bs0, kt + 32);   // step s+2
    GEMM_COMPUTE(As1, Bs1);          // step s+1
    GEMM_BOUNDARY;
    kt += 64;
  }
  GEMM_STAGE(As1, Bs1, kt);          // last step
  GEMM_COMPUTE(As0, Bs0);            // step nt-2
  GEMM_BOUNDARY;
  GEMM_COMPUTE(As1, Bs1);            // step nt-1 (no prefetch)

  // epilogue: C row = quad*4+reg, col = lane&15; scatter to original token
#pragma unroll
  for (int i = 0; i < 4; i++) {
#pragma unroll
    for (int rr = 0; rr < 4; rr++) {
      int rowg = bm * 128 + wm + i * 16 + quad * 4 + rr;
      int src = perm_src[rowg];
      if (src < 0) continue;
      size_t rowoff = (size_t)src * N + bn * 128 + wn + lr;
#pragma unroll
      for (int j = 0; j < 4; j++) {
        if (OUT_F32)
          ((float*)Cout)[rowoff + j * 16] = acc[i][j][rr];
        else
          ((bf16_t*)Cout)[rowoff + j * 16] = (bf16_t)acc[i][j][rr];
      }
    }
  }
}

// ---------------------------------------------------------------- RoPE + q/k split
__global__ __launch_bounds__(256) void rope_split(
    const bf16_t* __restrict__ mixed, const int* __restrict__ pos_ids,
    bf16_t* __restrict__ qbuf, bf16_t* __restrict__ kbuf) {
  int idx = blockIdx.x * 256 + threadIdx.x;
  int d2 = idx & 63;
  int h = (idx >> 6) & 31;
  int token = idx >> 11;
  int b = token >> 11;
  int l = token & (SEQ - 1);
  int pos = pos_ids[token];
  float inv = expf((float)d2 * -0.14391156831212787f);  // -ln(10000)/64
  float ang = (float)pos * inv;
  float c = cosf(ang), s = sinf(ang);

  const bf16_t* row = mixed + (size_t)token * QKV3;
  float q1 = (float)row[h * HD + d2];
  float q2 = (float)row[h * HD + d2 + 64];
  float k1 = (float)row[HID + h * HD + d2];
  float k2 = (float)row[HID + h * HD + d2 + 64];

  size_t base = ((size_t)(b * NH + h) * SEQ + l) * HD;
  qbuf[base + d2]      = (bf16_t)(q1 * c - q2 * s);
  qbuf[base + d2 + 64] = (bf16_t)(q2 * c + q1 * s);
  kbuf[base + d2]      = (bf16_t)(k1 * c - k2 * s);
  kbuf[base + d2 + 64] = (bf16_t)(k2 * c + k1 * s);
}

// ---------------------------------------------------------------- V transpose
__global__ __launch_bounds__(256) void vtrans(const bf16_t* __restrict__ mixed,
                                              bf16_t* __restrict__ vbuf) {
  __shared__ bf16_t tile[64][130];
  const int bh = blockIdx.x;
  const int lt = blockIdx.y;
  const int b = bh >> 5, h = bh & 31;
  const int tid = threadIdx.x;
#pragma unroll
  for (int i = 0; i < 32; i++) {
    int s = i * 256 + tid;
    int l = s >> 7, d = s & 127;
    size_t token = (size_t)b * SEQ + lt * 64 + l;
    tile[l][d] = mixed[token * QKV3 + 2 * HID + h * HD + d];
  }
  __syncthreads();
#pragma unroll
  for (int i = 0; i < 32; i++) {
    int s = i * 256 + tid;
    int d = s >> 6, l = s & 63;
    vbuf[((size_t)bh * HD + d) * SEQ + lt * 64 + l] = tile[l][d];
  }
}

// ---------------------------------------------------------------- flash attention
// Swizzled LDS: chunk (16B) of row r stored at chunkpos ^ (r&7).
// ctx written in GATHERED row order (ginv) for the routed dense GEMM.
__global__ __launch_bounds__(256) void attn_fwd(
    const bf16_t* __restrict__ qb, const bf16_t* __restrict__ kb,
    const bf16_t* __restrict__ vb, bf16_t* __restrict__ ctxg,
    const int* __restrict__ ginv) {
  __shared__ bf16_t Ks[64 * 128];      // [key][d], swizzled
  __shared__ bf16_t Vs[128 * 64];      // [d][key], swizzled
  __shared__ bf16_t Ps[4 * 32 * 64];   // per-wave P [32 q][64 key], swizzled
  const int bh = blockIdx.x, qt = blockIdx.y;
  const int b = bh >> 5, h = bh & 31;
  const int tid = threadIdx.x;
  const int wv = tid >> 6, lane = tid & 63, lr = lane & 15, quad = lane >> 4;
  const int qrow0 = qt * 128 + wv * 32;

  const bf16_t* qbase = qb + (size_t)bh * SEQ * HD;
  const bf16_t* kbase = kb + (size_t)bh * SEQ * HD;
  const bf16_t* vbase = vb + (size_t)bh * HD * SEQ;

  bf16x8 qf[2][4];
#pragma unroll
  for (int i = 0; i < 2; i++)
#pragma unroll
    for (int ds = 0; ds < 4; ds++)
      qf[i][ds] = *(const bf16x8*)(qbase + (size_t)(qrow0 + i * 16 + lr) * HD +
                                   ds * 32 + quad * 8);

  f32x4 O[2][8] = {};
  float mst[2][4], lst[2][4];
#pragma unroll
  for (int i = 0; i < 2; i++)
#pragma unroll
    for (int r = 0; r < 4; r++) { mst[i][r] = -1e30f; lst[i][r] = 0.f; }

  const float scale = 0.08838834764831845f;  // 1/sqrt(128)
  const int l7 = lr & 7;

  for (int kt = 0; kt < SEQ / 64; kt++) {
    const bf16_t* ksrc = kbase + (size_t)kt * 64 * HD;
    const bf16_t* vsrc = vbase + kt * 64;
#pragma unroll
    for (int inst = 0; inst < 4; inst++) {
      int s = inst * 256 + tid;
      int krow = s >> 4, kg = (s & 15) ^ (krow & 7);
      gld_lds16(ksrc + (size_t)krow * HD + kg * 8,
                &Ks[(inst * 256 + (tid & ~63)) * 8]);
      int vrow = s >> 3, vg = (s & 7) ^ (vrow & 7);
      gld_lds16(vsrc + (size_t)vrow * SEQ + vg * 8,
                &Vs[(inst * 256 + (tid & ~63)) * 8]);
    }
    __syncthreads();

    // S = Q @ K^T
    f32x4 S[2][4] = {};
#pragma unroll
    for (int ds = 0; ds < 4; ds++) {
      bf16x8 kf[4];
#pragma unroll
      for (int n = 0; n < 4; n++)
        kf[n] = *(const bf16x8*)&Ks[(n * 16 + lr) * HD +
                                    ((ds * 4 + quad) ^ l7) * 8];
#pragma unroll
      for (int i = 0; i < 2; i++)
#pragma unroll
        for (int n = 0; n < 4; n++)
          S[i][n] = __builtin_amdgcn_mfma_f32_16x16x32_bf16(qf[i][ds], kf[n],
                                                            S[i][n], 0, 0, 0);
    }

    bf16_t* pw = &Ps[wv * 32 * 64];
#pragma unroll
    for (int i = 0; i < 2; i++) {
      float rmax[4];
#pragma unroll
      for (int r = 0; r < 4; r++) {
        float m = -1e30f;
#pragma unroll
        for (int n = 0; n < 4; n++) {
          S[i][n][r] *= scale;
          m = fmaxf(m, S[i][n][r]);
        }
#pragma unroll
        for (int off = 1; off < 16; off <<= 1)
          m = fmaxf(m, __shfl_xor(m, off, 64));
        rmax[r] = m;
      }
#pragma unroll
      for (int r = 0; r < 4; r++) {
        float mnew = fmaxf(mst[i][r], rmax[r]);
        float alpha = __expf(mst[i][r] - mnew);
        mst[i][r] = mnew;
        float rsum = 0.f;
#pragma unroll
        for (int n = 0; n < 4; n++) {
          float p = __expf(S[i][n][r] - mnew);
          S[i][n][r] = p;
          rsum += p;
        }
#pragma unroll
        for (int off = 1; off < 16; off <<= 1) rsum += __shfl_xor(rsum, off, 64);
        lst[i][r] = lst[i][r] * alpha + rsum;
#pragma unroll
        for (int n = 0; n < 8; n++) O[i][n][r] *= alpha;
        int row = i * 16 + quad * 4 + r;
#pragma unroll
        for (int n = 0; n < 4; n++) {
          int e = n * 16 + lr;
          pw[row * 64 + (((e >> 3) ^ (row & 7)) * 8) + (e & 7)] =
              (bf16_t)S[i][n][r];
        }
      }
    }

    // O += P @ V
#pragma unroll
    for (int ks = 0; ks < 2; ks++) {
      bf16x8 pf[2], vf[8];
#pragma unroll
      for (int i = 0; i < 2; i++)
        pf[i] = *(const bf16x8*)&pw[(i * 16 + lr) * 64 +
                                    ((ks * 4 + quad) ^ l7) * 8];
#pragma unroll
      for (int n = 0; n < 8; n++)
        vf[n] = *(const bf16x8*)&Vs[(n * 16 + lr) * 64 +
                                    ((ks * 4 + quad) ^ l7) * 8];
#pragma unroll
      for (int i = 0; i < 2; i++)
#pragma unroll
        for (int n = 0; n < 8; n++)
          O[i][n] = __builtin_amdgcn_mfma_f32_16x16x32_bf16(pf[i], vf[n],
                                                            O[i][n], 0, 0, 0);
    }
    __syncthreads();
  }

  // epilogue: normalize, write ctx in GATHERED order
#pragma unroll
  for (int i = 0; i < 2; i++)
#pragma unroll
    for (int r = 0; r < 4; r++) {
      float inv = 1.0f / lst[i][r];
      int tok = b * SEQ + qt * 128 + wv * 32 + i * 16 + quad * 4 + r;
      size_t dst = (size_t)ginv[tok] * HID + h * HD;
#pragma unroll
      for (int n = 0; n < 8; n++)
        ctxg[dst + n * 16 + lr] = (bf16_t)(O[i][n][r] * inv);
    }
}

// ---------------------------------------------------------------- launch
extern "C" void kernel_launch(void* const* d_in, const int* in_sizes, int n_in,
                              void* d_out, int out_size, void* d_ws, size_t ws_size,
                              hipStream_t stream) {
  const float* hs  = (const float*)d_in[0];
  const int*   tt  = (const int*)d_in[1];
  const int*   pos = (const int*)d_in[2];
  // d_in[3] attention_mask: all zeros, unused
  const float* wvq = (const float*)d_in[4];
  const float* wlq = (const float*)d_in[5];
  const float* wvd = (const float*)d_in[6];
  const float* wld = (const float*)d_in[7];
  float* out = (float*)d_out;

  char* ws = (char*)d_ws;
  size_t off = 0;
  auto alloc = [&](size_t bytes) -> char* {
    char* p = ws + off;
    off += (bytes + 255) & ~(size_t)255;
    return p;
  };
  bf16_t* hsg   = (bf16_t*)alloc((size_t)MPAD * HID * 2);   // gathered hidden
  bf16_t* wvqb  = (bf16_t*)alloc((size_t)QKV3 * HID * 2);
  bf16_t* wlqb  = (bf16_t*)alloc((size_t)QKV3 * HID * 2);
  bf16_t* wvdb  = (bf16_t*)alloc((size_t)HID * HID * 2);
  bf16_t* wldb  = (bf16_t*)alloc((size_t)HID * HID * 2);
  bf16_t* mixed = (bf16_t*)alloc((size_t)NTOK * QKV3 * 2);  // token order
  bf16_t* qbuf  = (bf16_t*)alloc((size_t)NTOK * HID * 2);
  bf16_t* kbuf  = (bf16_t*)alloc((size_t)NTOK * HID * 2);
  bf16_t* vbuf  = (bf16_t*)alloc((size_t)NTOK * HID * 2);
  int* perm_src = (int*)alloc((size_t)MPAD * 4);
  int* ginv     = (int*)alloc((size_t)NTOK * 4);
  int* meta     = (int*)alloc(256);
  bf16_t* ctxg  = mixed;  // mixed dead after rope/vtrans; reuse (MPAD rows fit)

  scan_kernel<<<dim3(1), dim3(1024), 0, stream>>>(tt, perm_src, ginv, meta);

  cast_gather<<<dim3(NTOK * HID / 1024), dim3(256), 0, stream>>>(hs, hsg, ginv);
  auto cast = [&](const float* in, bf16_t* o, long long n) {
    castk<<<dim3((unsigned)((n + 1023) / 1024)), dim3(256), 0, stream>>>(in, o, n);
  };
  cast(wvq, wvqb, (long long)QKV3 * HID);
  cast(wlq, wlqb, (long long)QKV3 * HID);
  cast(wvd, wvdb, (long long)HID * HID);
  cast(wld, wldb, (long long)HID * HID);

  // routed QKV: one GEMM, expert chosen per M-tile, scatter to token order
  // 1-D grid: GM * (N/128) blocks, XCD-swizzled in-kernel
  gemm_routed<0><<<dim3(GM * (QKV3 / 128)), dim3(256), 0, stream>>>(
      hsg, wvqb, wlqb, mixed, QKV3, HID, perm_src, meta);

  rope_split<<<dim3((NTOK * NH * 64) / 256), dim3(256), 0, stream>>>(mixed, pos,
                                                                     qbuf, kbuf);
  vtrans<<<dim3(BSZ * NH, SEQ / 64), dim3(256), 0, stream>>>(mixed, vbuf);

  attn_fwd<<<dim3(BSZ * NH, SEQ / 128), dim3(256), 0, stream>>>(qbuf, kbuf, vbuf,
                                                                ctxg, ginv);

  // routed dense out (fp32), scatter rows to d_out token order
  gemm_routed<1><<<dim3(GM * (HID / 128)), dim3(256), 0, stream>>>(
      ctxg, wvdb, wldb, out, HID, HID, perm_src, meta);
}

// Round 2
// 1836.107 us; speedup vs baseline: 1.1795x; 1.0545x over previous
//
#include <hip/hip_runtime.h>
#include <hip/hip_bf16.h>
#include <math.h>

// ---------------------------------------------------------------------------
// VisionExpertAttention on MI355X (gfx950) — round 4
//   * expert ROUTING via device-side scan + gathered rows (halves GEMM FLOPs)
//   * GEMM: 256x256 8-phase schedule (m201 template, plain HIP):
//       - 512 thr / 8 waves (2M x 4N), wave tile 128x64, BK=64
//       - LDS 128 KiB: 2 buffers x (A 256x64 + B 256x64) bf16
//       - per phase: ds-read subtile || stage 1 half-tile (2 gld_lds) ->
//         barrier -> 16 MFMA (one C-quadrant) -> barrier
//       - counted vmcnt(6) ONLY at phases 4 and 8 (3 half-tiles in flight,
//         never drain to 0 in the main loop)  [T3+T4]
//       - setprio(1) around MFMA clusters                [T5]
//       - XCD-chunked 1-D grid, bm-inner                 [T1]
//       - chunk^row XOR swizzle on 16B chunks, applied to the GLOBAL source
//         (global_load_lds writes linearly) and on ds_read -> 2-way = free
//     Schedule invariant: a region is staged only after the phase that
//     consumed it (B-frags all read in P1 -> B free P2/P3; A halves free
//     after P3). vmcnt(6) at P4/P8 proves the next-computed tile landed.
//   * vision rows padded to 256 (was 128) so no 256-row M-tile mixes experts
// ---------------------------------------------------------------------------

typedef __bf16 bf16_t;
typedef __bf16 bf16x8 __attribute__((ext_vector_type(8)));
typedef __bf16 bf16x4 __attribute__((ext_vector_type(4)));
typedef float  f32x4  __attribute__((ext_vector_type(4)));

#define BSZ   2
#define SEQ   2048
#define NTOK  (BSZ * SEQ)     // 4096
#define MPAD  (NTOK + 256)    // 4352 gathered rows (vision padded to 256)
#define HID   4096
#define NH    32
#define HD    128
#define QKV3  (3 * HID)       // 12288
#define GM    (MPAD / 256)    // 17 M-tiles of 256

__device__ __forceinline__ void gld_lds16(const bf16_t* g, bf16_t* l) {
  __builtin_amdgcn_global_load_lds(
      (const __attribute__((address_space(1))) unsigned int*)g,
      (__attribute__((address_space(3))) unsigned int*)l, 16, 0, 0);
}

// ---------------------------------------------------------------- cast f32->bf16
__global__ __launch_bounds__(256) void castk(const float* __restrict__ in,
                                             bf16_t* __restrict__ out,
                                             long long n) {
  long long i = ((long long)blockIdx.x * 256 + threadIdx.x) * 4;
  if (i >= n) return;
  float4 v = *(const float4*)(in + i);
  bf16x4 o;
  o[0] = (bf16_t)v.x; o[1] = (bf16_t)v.y; o[2] = (bf16_t)v.z; o[3] = (bf16_t)v.w;
  *(bf16x4*)(out + i) = o;
}

// ------------------------------------------------- cast + gather hidden rows
__global__ __launch_bounds__(256) void cast_gather(const float* __restrict__ in,
                                                   bf16_t* __restrict__ out,
                                                   const int* __restrict__ ginv) {
  long long i = ((long long)blockIdx.x * 256 + threadIdx.x) * 4;
  int token = (int)(i >> 12);        // HID = 4096
  int col = (int)(i & 4095);
  float4 v = *(const float4*)(in + i);
  bf16x4 o;
  o[0] = (bf16_t)v.x; o[1] = (bf16_t)v.y; o[2] = (bf16_t)v.z; o[3] = (bf16_t)v.w;
  *(bf16x4*)(out + (size_t)ginv[token] * HID + col) = o;
}

// ---------------------------------------------------------------- routing scan
// vision iff tt[l]==1 && tt[l+1]==1 (l < SEQ-1). vision tokens -> rows
// [0,nv), pad to 256; language -> [nvpad, nvpad+nl). perm_src[dst]=token or
// -1 (pad), ginv[token]=dst, meta[0]=nvpad/256 (# vision M-tiles).
__global__ __launch_bounds__(1024) void scan_kernel(const int* __restrict__ tt,
                                                    int* __restrict__ perm_src,
                                                    int* __restrict__ ginv,
                                                    int* __restrict__ meta) {
  __shared__ int sums[1024];
  const int t = threadIdx.x;
  for (int i = t; i < MPAD; i += 1024) perm_src[i] = -1;
  int v[4], s = 0;
#pragma unroll
  for (int j = 0; j < 4; j++) {
    int tok = t * 4 + j;
    int l = tok & (SEQ - 1);
    int vis = (l < SEQ - 1) && (tt[tok] == 1) && (tt[tok + 1] == 1);
    v[j] = vis; s += vis;
  }
  sums[t] = s;
  __syncthreads();
  for (int off = 1; off < 1024; off <<= 1) {
    int x = sums[t];
    int y = (t >= off) ? sums[t - off] : 0;
    __syncthreads();
    sums[t] = x + y;
    __syncthreads();
  }
  const int nv = sums[1023];
  const int nvpad = (nv + 255) & ~255;
  int pv = sums[t] - s;  // vision count strictly before this thread's tokens
#pragma unroll
  for (int j = 0; j < 4; j++) {
    int tok = t * 4 + j;
    int dst;
    if (v[j]) { dst = pv; pv++; }
    else      { dst = nvpad + (tok - pv); }
    perm_src[dst] = tok;
    ginv[tok] = dst;
  }
  if (t == 0) meta[0] = nvpad >> 8;
}

// ------------------------------------------- routed GEMM C = A_g @ B_e^T
// A [MPAD,K] gathered bf16; B chosen per 256-row M-tile (vision tiles
// first). Epilogue scatters row perm_src[row_g] (skip -1).

#define BAR                                  \
  do {                                       \
    asm volatile("" ::: "memory");           \
    __builtin_amdgcn_s_barrier();            \
    asm volatile("" ::: "memory");           \
  } while (0)

#define VMW(N) asm volatile("s_waitcnt vmcnt(" #N ")" ::: "memory")

// ds-read A-half mh (8 x b128) / B full (8 x b128). byte layout within a
// 256x64 tile: row*128 + (chunk ^ (row&7))*16 ; frag rows are 16-aligned
// +lr so row&7 == lr&7 (lane-constant).
#define LDA(BUF, mh)                                                       \
  _Pragma("unroll") for (int m_ = 0; m_ < 4; m_++)                         \
    _Pragma("unroll") for (int kk_ = 0; kk_ < 2; kk_++)                    \
      af[m_][kk_] = *(const bf16x8*)((const char*)As[BUF] +                \
          (size_t)((wr * 128 + (mh) * 64 + m_ * 16 + lr) * 128 +           \
                   (((kk_ * 4 + quad) ^ l7) * 16)));

#define LDB(BUF)                                                           \
  _Pragma("unroll") for (int n_ = 0; n_ < 4; n_++)                         \
    _Pragma("unroll") for (int kk_ = 0; kk_ < 2; kk_++)                    \
      bfr[n_][kk_] = *(const bf16x8*)((const char*)Bs[BUF] +               \
          (size_t)((wc * 64 + n_ * 16 + lr) * 128 +                        \
                   (((kk_ * 4 + quad) ^ l7) * 16)));

// one C-quadrant (mh,nh): 4m x 2n x 2kk = 16 MFMA, kk outermost so
// dependent same-acc MFMAs are 8 apart.
#define MMQ(mh, nh)                                                        \
  __builtin_amdgcn_s_setprio(1);                                           \
  _Pragma("unroll") for (int kk_ = 0; kk_ < 2; kk_++)                      \
    _Pragma("unroll") for (int m_ = 0; m_ < 4; m_++)                       \
      _Pragma("unroll") for (int n_ = 0; n_ < 2; n_++)                     \
        acc[(mh) * 4 + m_][(nh) * 2 + n_] =                                \
            __builtin_amdgcn_mfma_f32_16x16x32_bf16(                       \
                af[m_][kk_], bfr[(nh) * 2 + n_][kk_],                      \
                acc[(mh) * 4 + m_][(nh) * 2 + n_], 0, 0, 0);               \
  __builtin_amdgcn_s_setprio(0);

template <int OUT_F32>
__global__ __launch_bounds__(512, 2) void gemm_routed(
    const bf16_t* __restrict__ A, const bf16_t* __restrict__ Bv,
    const bf16_t* __restrict__ Bl, void* __restrict__ Cout, int N, int K,
    const int* __restrict__ perm_src, const int* __restrict__ meta) {
  __shared__ bf16_t As[2][256 * 64];
  __shared__ bf16_t Bs[2][256 * 64];
  const int tid = threadIdx.x;
  const int wv = tid >> 6, lane = tid & 63;
  const int lr = lane & 15, quad = lane >> 4, l7 = lr & 7;
  const int wr = wv >> 2, wc = wv & 3;   // wave grid 2(M) x 4(N)

  // T1: bijective XCD chunking, bm fastest within a chunk.
  const int nwg = gridDim.x;
  const int q = nwg >> 3, r = nwg & 7;
  const int xcd = blockIdx.x & 7, pos = blockIdx.x >> 3;
  const int wgid = (xcd < r ? xcd * (q + 1) : r * (q + 1) + (xcd - r) * q) + pos;
  const int bm = wgid % GM;
  const int bn = wgid / GM;
  const bf16_t* __restrict__ Bp = (bm < meta[0]) ? Bv : Bl;

  const bf16_t* Ab = A + (size_t)(bm * 256) * K;
  const bf16_t* Bb = Bp + (size_t)(bn * 256) * K;

  // staging lane constants. Per gld instruction a wave fills one 1KB slice
  // (8 rows x 128B); slice s = wv*2+j; lane -> row s*8+(lane>>3), global
  // chunk (lane&7)^(lane>>3) (inverse swizzle; LDS dest stays linear).
  const int srow = lane >> 3;
  const int schunk = (lane & 7) ^ srow;
  auto stage = [&](bf16_t* ldsbase, const bf16_t* gbase) {
#pragma unroll
    for (int j = 0; j < 2; j++) {
      int s = wv * 2 + j;
      gld_lds16(gbase + (size_t)(s * 8 + srow) * K + schunk * 8,
                ldsbase + s * 512);
    }
  };

  f32x4 acc[8][4] = {};
  bf16x8 af[4][2], bfr[4][2];

  const size_t KH = 128 * (size_t)K;  // half-tile row jump

  // ---- prologue: tile0 -> buf0 (4 halves), tile1 -> buf1 {Bh0,Bh1,Ah0}
  stage(&Bs[0][0],    Bb);
  stage(&Bs[0][8192], Bb + KH);
  stage(&As[0][0],    Ab);
  stage(&As[0][8192], Ab + KH);
  stage(&Bs[1][0],    Bb + 64);
  stage(&Bs[1][8192], Bb + KH + 64);
  stage(&As[1][0],    Ab + 64);
  VMW(6);  // oldest 8 (= all of tile 0) landed
  BAR;

  // ---- steady: iter i computes tiles 2i (buf0) and 2i+1 (buf1)
  for (int i = 0; i < (K >> 7) - 1; ++i) {
    const size_t c1 = (size_t)(2 * i + 1) * 64;  // col of tile 2i+1
    const size_t c2 = c1 + 64, c3 = c1 + 128;
    // P1: reads buf0 A-mh0 + B-full; stages buf1.Ah1 (tile 2i+1)
    LDA(0, 0); LDB(0);
    stage(&As[1][8192], Ab + KH + c1);
    BAR; MMQ(0, 0); BAR;
    // P2: buf0.B consumed in P1 -> stage buf0.Bh0 (tile 2i+2)
    stage(&Bs[0][0], Bb + c2);
    BAR; MMQ(0, 1); BAR;
    // P3: reads buf0 A-mh1; stage buf0.Bh1 (tile 2i+2)
    LDA(0, 1);
    stage(&Bs[0][8192], Bb + KH + c2);
    BAR; MMQ(1, 1); BAR;
    // P4: buf0.A consumed by P3 -> stage buf0.Ah0; vmcnt(6) proves tile
    // 2i+1 (staged P6..P8 prev iter + P1 this iter) fully landed.
    stage(&As[0][0], Ab + c2);
    BAR; MMQ(1, 0); VMW(6); BAR;
    // P5: reads buf1 A-mh0 + B-full; stage buf0.Ah1 (tile 2i+2)
    LDA(1, 0); LDB(1);
    stage(&As[0][8192], Ab + KH + c2);
    BAR; MMQ(0, 0); BAR;
    // P6: buf1.B consumed in P5 -> stage buf1.Bh0 (tile 2i+3)
    stage(&Bs[1][0], Bb + c3);
    BAR; MMQ(0, 1); BAR;
    // P7: reads buf1 A-mh1; stage buf1.Bh1 (tile 2i+3)
    LDA(1, 1);
    stage(&Bs[1][8192], Bb + KH + c3);
    BAR; MMQ(1, 1); BAR;
    // P8: stage buf1.Ah0 (tile 2i+3); vmcnt(6) proves tile 2i+2 landed.
    stage(&As[1][0], Ab + c3);
    BAR; MMQ(1, 0); VMW(6); BAR;
  }

  // ---- tail: tiles K/64-2 (buf0), K/64-1 (buf1); only buf1.Ah1 to stage
  {
    const size_t cl = (size_t)((K >> 6) - 1) * 64;
    LDA(0, 0); LDB(0);
    stage(&As[1][8192], Ab + KH + cl);
    BAR; MMQ(0, 0); BAR;
    BAR; MMQ(0, 1); BAR;
    LDA(0, 1);
    BAR; MMQ(1, 1); BAR;
    BAR; MMQ(1, 0); VMW(0); BAR;   // drain: last tile fully landed
    LDA(1, 0); LDB(1);
    BAR; MMQ(0, 0); BAR;
    BAR; MMQ(0, 1); BAR;
    LDA(1, 1);
    BAR; MMQ(1, 1); BAR;
    BAR; MMQ(1, 0);
  }

  // epilogue: C row = quad*4+reg (A side), col = lr (B side); scatter rows
#pragma unroll
  for (int m = 0; m < 8; m++) {
#pragma unroll
    for (int rr = 0; rr < 4; rr++) {
      int rowg = bm * 256 + wr * 128 + m * 16 + quad * 4 + rr;
      int src = perm_src[rowg];
      if (src < 0) continue;
      size_t rowoff = (size_t)src * N + bn * 256 + wc * 64 + lr;
#pragma unroll
      for (int n = 0; n < 4; n++) {
        if (OUT_F32)
          ((float*)Cout)[rowoff + n * 16] = acc[m][n][rr];
        else
          ((bf16_t*)Cout)[rowoff + n * 16] = (bf16_t)acc[m][n][rr];
      }
    }
  }
}

// ---------------------------------------------------------------- RoPE + q/k split
__global__ __launch_bounds__(256) void rope_split(
    const bf16_t* __restrict__ mixed, const int* __restrict__ pos_ids,
    bf16_t* __restrict__ qbuf, bf16_t* __restrict__ kbuf) {
  int idx = blockIdx.x * 256 + threadIdx.x;
  int d2 = idx & 63;
  int h = (idx >> 6) & 31;
  int token = idx >> 11;
  int b = token >> 11;
  int l = token & (SEQ - 1);
  int pos = pos_ids[token];
  float inv = expf((float)d2 * -0.14391156831212787f);  // -ln(10000)/64
  float ang = (float)pos * inv;
  float c = cosf(ang), s = sinf(ang);

  const bf16_t* row = mixed + (size_t)token * QKV3;
  float q1 = (float)row[h * HD + d2];
  float q2 = (float)row[h * HD + d2 + 64];
  float k1 = (float)row[HID + h * HD + d2];
  float k2 = (float)row[HID + h * HD + d2 + 64];

  size_t base = ((size_t)(b * NH + h) * SEQ + l) * HD;
  qbuf[base + d2]      = (bf16_t)(q1 * c - q2 * s);
  qbuf[base + d2 + 64] = (bf16_t)(q2 * c + q1 * s);
  kbuf[base + d2]      = (bf16_t)(k1 * c - k2 * s);
  kbuf[base + d2 + 64] = (bf16_t)(k2 * c + k1 * s);
}

// ---------------------------------------------------------------- V transpose
__global__ __launch_bounds__(256) void vtrans(const bf16_t* __restrict__ mixed,
                                              bf16_t* __restrict__ vbuf) {
  __shared__ bf16_t tile[64][130];
  const int bh = blockIdx.x;
  const int lt = blockIdx.y;
  const int b = bh >> 5, h = bh & 31;
  const int tid = threadIdx.x;
#pragma unroll
  for (int i = 0; i < 32; i++) {
    int s = i * 256 + tid;
    int l = s >> 7, d = s & 127;
    size_t token = (size_t)b * SEQ + lt * 64 + l;
    tile[l][d] = mixed[token * QKV3 + 2 * HID + h * HD + d];
  }
  __syncthreads();
#pragma unroll
  for (int i = 0; i < 32; i++) {
    int s = i * 256 + tid;
    int d = s >> 6, l = s & 63;
    vbuf[((size_t)bh * HD + d) * SEQ + lt * 64 + l] = tile[l][d];
  }
}

// ---------------------------------------------------------------- flash attention
// Swizzled LDS: chunk (16B) of row r stored at chunkpos ^ (r&7).
// ctx written in GATHERED row order (ginv) for the routed dense GEMM.
__global__ __launch_bounds__(256) void attn_fwd(
    const bf16_t* __restrict__ qb, const bf16_t* __restrict__ kb,
    const bf16_t* __restrict__ vb, bf16_t* __restrict__ ctxg,
    const int* __restrict__ ginv) {
  __shared__ bf16_t Ks[64 * 128];      // [key][d], swizzled
  __shared__ bf16_t Vs[128 * 64];      // [d][key], swizzled
  __shared__ bf16_t Ps[4 * 32 * 64];   // per-wave P [32 q][64 key], swizzled
  const int bh = blockIdx.x, qt = blockIdx.y;
  const int b = bh >> 5, h = bh & 31;
  const int tid = threadIdx.x;
  const int wv = tid >> 6, lane = tid & 63, lr = lane & 15, quad = lane >> 4;
  const int qrow0 = qt * 128 + wv * 32;

  const bf16_t* qbase = qb + (size_t)bh * SEQ * HD;
  const bf16_t* kbase = kb + (size_t)bh * SEQ * HD;
  const bf16_t* vbase = vb + (size_t)bh * HD * SEQ;

  bf16x8 qf[2][4];
#pragma unroll
  for (int i = 0; i < 2; i++)
#pragma unroll
    for (int ds = 0; ds < 4; ds++)
      qf[i][ds] = *(const bf16x8*)(qbase + (size_t)(qrow0 + i * 16 + lr) * HD +
                                   ds * 32 + quad * 8);

  f32x4 O[2][8] = {};
  float mst[2][4], lst[2][4];
#pragma unroll
  for (int i = 0; i < 2; i++)
#pragma unroll
    for (int r = 0; r < 4; r++) { mst[i][r] = -1e30f; lst[i][r] = 0.f; }

  const float scale = 0.08838834764831845f;  // 1/sqrt(128)
  const int l7 = lr & 7;

  for (int kt = 0; kt < SEQ / 64; kt++) {
    const bf16_t* ksrc = kbase + (size_t)kt * 64 * HD;
    const bf16_t* vsrc = vbase + kt * 64;
#pragma unroll
    for (int inst = 0; inst < 4; inst++) {
      int s = inst * 256 + tid;
      int krow = s >> 4, kg = (s & 15) ^ (krow & 7);
      gld_lds16(ksrc + (size_t)krow * HD + kg * 8,
                &Ks[(inst * 256 + (tid & ~63)) * 8]);
      int vrow = s >> 3, vg = (s & 7) ^ (vrow & 7);
      gld_lds16(vsrc + (size_t)vrow * SEQ + vg * 8,
                &Vs[(inst * 256 + (tid & ~63)) * 8]);
    }
    __syncthreads();

    // S = Q @ K^T
    f32x4 S[2][4] = {};
#pragma unroll
    for (int ds = 0; ds < 4; ds++) {
      bf16x8 kf[4];
#pragma unroll
      for (int n = 0; n < 4; n++)
        kf[n] = *(const bf16x8*)&Ks[(n * 16 + lr) * HD +
                                    ((ds * 4 + quad) ^ l7) * 8];
#pragma unroll
      for (int i = 0; i < 2; i++)
#pragma unroll
        for (int n = 0; n < 4; n++)
          S[i][n] = __builtin_amdgcn_mfma_f32_16x16x32_bf16(qf[i][ds], kf[n],
                                                            S[i][n], 0, 0, 0);
    }

    bf16_t* pw = &Ps[wv * 32 * 64];
#pragma unroll
    for (int i = 0; i < 2; i++) {
      float rmax[4];
#pragma unroll
      for (int r = 0; r < 4; r++) {
        float m = -1e30f;
#pragma unroll
        for (int n = 0; n < 4; n++) {
          S[i][n][r] *= scale;
          m = fmaxf(m, S[i][n][r]);
        }
#pragma unroll
        for (int off = 1; off < 16; off <<= 1)
          m = fmaxf(m, __shfl_xor(m, off, 64));
        rmax[r] = m;
      }
#pragma unroll
      for (int r = 0; r < 4; r++) {
        float mnew = fmaxf(mst[i][r], rmax[r]);
        float alpha = __expf(mst[i][r] - mnew);
        mst[i][r] = mnew;
        float rsum = 0.f;
#pragma unroll
        for (int n = 0; n < 4; n++) {
          float p = __expf(S[i][n][r] - mnew);
          S[i][n][r] = p;
          rsum += p;
        }
#pragma unroll
        for (int off = 1; off < 16; off <<= 1) rsum += __shfl_xor(rsum, off, 64);
        lst[i][r] = lst[i][r] * alpha + rsum;
#pragma unroll
        for (int n = 0; n < 8; n++) O[i][n][r] *= alpha;
        int row = i * 16 + quad * 4 + r;
#pragma unroll
        for (int n = 0; n < 4; n++) {
          int e = n * 16 + lr;
          pw[row * 64 + (((e >> 3) ^ (row & 7)) * 8) + (e & 7)] =
              (bf16_t)S[i][n][r];
        }
      }
    }

    // O += P @ V
#pragma unroll
    for (int ks = 0; ks < 2; ks++) {
      bf16x8 pf[2], vf[8];
#pragma unroll
      for (int i = 0; i < 2; i++)
        pf[i] = *(const bf16x8*)&pw[(i * 16 + lr) * 64 +
                                    ((ks * 4 + quad) ^ l7) * 8];
#pragma unroll
      for (int n = 0; n < 8; n++)
        vf[n] = *(const bf16x8*)&Vs[(n * 16 + lr) * 64 +
                                    ((ks * 4 + quad) ^ l7) * 8];
#pragma unroll
      for (int i = 0; i < 2; i++)
#pragma unroll
        for (int n = 0; n < 8; n++)
          O[i][n] = __builtin_amdgcn_mfma_f32_16x16x32_bf16(pf[i], vf[n],
                                                            O[i][n], 0, 0, 0);
    }
    __syncthreads();
  }

  // epilogue: normalize, write ctx in GATHERED order
#pragma unroll
  for (int i = 0; i < 2; i++)
#pragma unroll
    for (int r = 0; r < 4; r++) {
      float inv = 1.0f / lst[i][r];
      int tok = b * SEQ + qt * 128 + wv * 32 + i * 16 + quad * 4 + r;
      size_t dst = (size_t)ginv[tok] * HID + h * HD;
#pragma unroll
      for (int n = 0; n < 8; n++)
        ctxg[dst + n * 16 + lr] = (bf16_t)(O[i][n][r] * inv);
    }
}

// ---------------------------------------------------------------- launch
extern "C" void kernel_launch(void* const* d_in, const int* in_sizes, int n_in,
                              void* d_out, int out_size, void* d_ws, size_t ws_size,
                              hipStream_t stream) {
  const float* hs  = (const float*)d_in[0];
  const int*   tt  = (const int*)d_in[1];
  const int*   pos = (const int*)d_in[2];
  // d_in[3] attention_mask: all zeros, unused
  const float* wvq = (const float*)d_in[4];
  const float* wlq = (const float*)d_in[5];
  const float* wvd = (const float*)d_in[6];
  const float* wld = (const float*)d_in[7];
  float* out = (float*)d_out;

  char* ws = (char*)d_ws;
  size_t off = 0;
  auto alloc = [&](size_t bytes) -> char* {
    char* p = ws + off;
    off += (bytes + 255) & ~(size_t)255;
    return p;
  };
  bf16_t* hsg   = (bf16_t*)alloc((size_t)MPAD * HID * 2);   // gathered hidden
  bf16_t* wvqb  = (bf16_t*)alloc((size_t)QKV3 * HID * 2);
  bf16_t* wlqb  = (bf16_t*)alloc((size_t)QKV3 * HID * 2);
  bf16_t* wvdb  = (bf16_t*)alloc((size_t)HID * HID * 2);
  bf16_t* wldb  = (bf16_t*)alloc((size_t)HID * HID * 2);
  bf16_t* mixed = (bf16_t*)alloc((size_t)NTOK * QKV3 * 2);  // token order
  bf16_t* qbuf  = (bf16_t*)alloc((size_t)NTOK * HID * 2);
  bf16_t* kbuf  = (bf16_t*)alloc((size_t)NTOK * HID * 2);
  bf16_t* vbuf  = (bf16_t*)alloc((size_t)NTOK * HID * 2);
  int* perm_src = (int*)alloc((size_t)MPAD * 4);
  int* ginv     = (int*)alloc((size_t)NTOK * 4);
  int* meta     = (int*)alloc(256);
  bf16_t* ctxg  = mixed;  // mixed dead after rope/vtrans; reuse (MPAD rows fit)

  scan_kernel<<<dim3(1), dim3(1024), 0, stream>>>(tt, perm_src, ginv, meta);

  cast_gather<<<dim3(NTOK * HID / 1024), dim3(256), 0, stream>>>(hs, hsg, ginv);
  auto cast = [&](const float* in, bf16_t* o, long long n) {
    castk<<<dim3((unsigned)((n + 1023) / 1024)), dim3(256), 0, stream>>>(in, o, n);
  };
  cast(wvq, wvqb, (long long)QKV3 * HID);
  cast(wlq, wlqb, (long long)QKV3 * HID);
  cast(wvd, wvdb, (long long)HID * HID);
  cast(wld, wldb, (long long)HID * HID);

  // routed QKV: one GEMM, expert chosen per 256-row M-tile
  gemm_routed<0><<<dim3(GM * (QKV3 / 256)), dim3(512), 0, stream>>>(
      hsg, wvqb, wlqb, mixed, QKV3, HID, perm_src, meta);

  rope_split<<<dim3((NTOK * NH * 64) / 256), dim3(256), 0, stream>>>(mixed, pos,
                                                                     qbuf, kbuf);
  vtrans<<<dim3(BSZ * NH, SEQ / 64), dim3(256), 0, stream>>>(mixed, vbuf);

  attn_fwd<<<dim3(BSZ * NH, SEQ / 128), dim3(256), 0, stream>>>(qbuf, kbuf, vbuf,
                                                                ctxg, ginv);

  // routed dense out (fp32), scatter rows to d_out token order
  gemm_routed<1><<<dim3(GM * (HID / 256)), dim3(512), 0, stream>>>(
      ctxg, wvdb, wldb, out, HID, HID, perm_src, meta);
}